// Round 1
// baseline (564.369 us; speedup 1.0000x reference)
//
#include <hip/hip_runtime.h>
#include <math.h>

// LocalSTD: out = sqrt( G*x^2 - (G*x)^2 + 1e-6 ), G = 11x11 Gaussian (sigma=1),
// depthwise, zero 'SAME' padding. Separable: two 1D 11-tap passes.
//
// Layout: x is [16, 64, 256, 256] fp32 = 1024 images of 256x256.
// Block = 256 threads (one per column) x 32 output rows; grid = (8 bands, 1024 imgs).
// LDS holds 42 input rows (32 + 5 halo each side) with 8-col zero pads -> branchless
// horizontal pass. Vertical pass accumulates in registers (fully unrolled).

#define BH 32          // output rows per block
#define XR 42          // input rows staged = BH + 10
#define XS 272         // LDS row stride in floats: 8 pad + 256 + 8 pad
#define W  256
#define IMG_PIX (256 * 256)

__global__ __launch_bounds__(256) void
local_std_kernel(const float* __restrict__ x, float* __restrict__ out)
{
    __shared__ float sx[XR * XS];   // 44.6 KB -> 3 blocks/CU

    const int t    = threadIdx.x;
    const int band = blockIdx.x;
    const int img  = blockIdx.y;
    const float* xi = x + (size_t)img * IMG_PIX;

    // Zero the horizontal pad columns ([0,8) and [264,272) of each row).
    for (int idx = t; idx < XR * 16; idx += 256) {
        int row = idx >> 4, p = idx & 15;
        int col = (p < 8) ? p : (256 + p);   // p in [8,16) -> col in [264,272)
        sx[row * XS + col] = 0.0f;
    }

    // Stage 42 rows x 256 cols as float4 (zero rows outside the image).
    const int r0 = band * BH - 5;
    for (int idx = t; idx < XR * 64; idx += 256) {
        int row = idx >> 6, c4 = idx & 63;
        int gr = r0 + row;
        float4 v = make_float4(0.f, 0.f, 0.f, 0.f);
        if (gr >= 0 && gr < 256)
            v = *(const float4*)(xi + gr * W + c4 * 4);
        *(float4*)(&sx[row * XS + 8 + c4 * 4]) = v;
    }
    __syncthreads();

    // Normalized 1D Gaussian, sigma=1, taps at d = j-5. (Truncated-sum
    // normalization differs from 1/sqrt(2pi) by ~9e-9 relative -> below fp32 ulp.)
    constexpr float GW[11] = {
        1.4867195e-06f, 1.3383023e-04f, 4.4318485e-03f, 5.3990965e-02f,
        2.4197072e-01f, 3.9894228e-01f, 2.4197072e-01f, 5.3990965e-02f,
        4.4318485e-03f, 1.3383023e-04f, 1.4867195e-06f
    };

    float acc1[BH], acc2[BH];
    #pragma unroll
    for (int i = 0; i < BH; ++i) { acc1[i] = 0.f; acc2[i] = 0.f; }

    const int c = t;   // this thread's column
    #pragma unroll
    for (int r = 0; r < XR; ++r) {
        // Horizontal 11-tap pass at (row r, col c): window is LDS cols c+3 .. c+13.
        const float* rowp = &sx[r * XS + 3 + c];
        float hx = 0.f, hx2 = 0.f;
        #pragma unroll
        for (int j = 0; j < 11; ++j) {
            float v  = rowp[j];
            float gv = GW[j] * v;
            hx  += gv;                    // sum g*x
            hx2  = fmaf(gv, v, hx2);      // sum g*x^2
        }
        // Vertical scatter: out row ro (local) uses input rows ro..ro+10 with
        // weight GW[r - ro]. Fully unrolled -> acc stays in registers.
        #pragma unroll
        for (int i = 0; i < 11; ++i) {
            int ro = r - 10 + i;
            if (ro >= 0 && ro < BH) {
                float w = GW[10 - i];     // = GW[r - ro]
                acc1[ro] = fmaf(w, hx,  acc1[ro]);
                acc2[ro] = fmaf(w, hx2, acc2[ro]);
            }
        }
    }

    float* oi = out + (size_t)img * IMG_PIX + (size_t)(band * BH) * W + c;
    #pragma unroll
    for (int ro = 0; ro < BH; ++ro) {
        float m   = acc1[ro];
        float var = acc2[ro] - m * m + 1e-6f;
        oi[(size_t)ro * W] = sqrtf(var);
    }
}

extern "C" void kernel_launch(void* const* d_in, const int* in_sizes, int n_in,
                              void* d_out, int out_size, void* d_ws, size_t ws_size,
                              hipStream_t stream)
{
    const float* x  = (const float*)d_in[0];
    float* out      = (float*)d_out;
    const int n_img = in_sizes[0] / IMG_PIX;       // 16*64 = 1024
    dim3 grid(W / BH, n_img);                      // (8, 1024)
    local_std_kernel<<<grid, 256, 0, stream>>>(x, out);
}

// Round 3
// 460.993 us; speedup vs baseline: 1.2242x; 1.2242x over previous
//
#include <hip/hip_runtime.h>
#include <math.h>

// LocalSTD: out = sqrt( G*x^2 - (G*x)^2 + 1e-6 ), G = 11x11 Gaussian (sigma=1),
// separable. x: [16,64,256,256] fp32 = 1024 images of 256x256.
//
// R3: one block per image, 4 waves/block, each wave sweeps a 64-row band.
// Wave = 64 lanes x 4 cols = full 256-col row. Vertical 11-tap from an 11-row
// float4 register ring (prefetch-by-1 on the incoming row). Horizontal 11-tap
// via wave-private LDS row buffers (v1,v2): each lane writes its float4, reads
// the 4 NEIGHBOR float4s (own comes from register), all ds_*_b128.
// Wave-synchronous LDS needs explicit fences: without them the scheduler hoists
// the (per-thread non-aliasing) neighbor reads above the writes -> R2's NaN.

#define W        256
#define IMG_PIX  (W * W)
#define BANDH    64          // output rows per wave
#define LDSW     272         // 8 zero-pad + 256 + 8 zero-pad

// normalized 1D Gaussian sigma=1 (2D kernel = outer product, sums factorize)
#define GW0 1.4867195e-06f   // |d|=5
#define GW1 1.3383023e-04f   // |d|=4
#define GW2 4.4318485e-03f   // |d|=3
#define GW3 5.3990965e-02f   // |d|=2
#define GW4 2.4197072e-01f   // |d|=1
#define GW5 3.9894228e-01f   // center

__device__ __forceinline__ float4 f4add(float4 a, float4 b) {
    return make_float4(a.x + b.x, a.y + b.y, a.z + b.z, a.w + b.w);
}
__device__ __forceinline__ float4 f4mul(float4 a, float4 b) {
    return make_float4(a.x * b.x, a.y * b.y, a.z * b.z, a.w * b.w);
}
__device__ __forceinline__ float4 f4scale(float g, float4 a) {
    return make_float4(g * a.x, g * a.y, g * a.z, g * a.w);
}
__device__ __forceinline__ float4 f4fma(float g, float4 a, float4 b) {
    return make_float4(fmaf(g, a.x, b.x), fmaf(g, a.y, b.y),
                       fmaf(g, a.z, b.z), fmaf(g, a.w, b.w));
}

// RAW fence: drain LDS pipe so neighbor lanes' writes are visible; the memory
// clobber pins instruction order against the scheduler.
__device__ __forceinline__ void lds_fence_hard() {
    __asm__ volatile("s_waitcnt lgkmcnt(0)" ::: "memory");
}
// WAR fence: compiler-only; keeps next iteration's writes below this
// iteration's reads (DS pipe is in-order per wave).
__device__ __forceinline__ void lds_fence_order() {
    __asm__ volatile("" ::: "memory");
}

__device__ __forceinline__ float4 load_row(const float* __restrict__ xi, int gr, int c) {
    if ((unsigned)gr < (unsigned)W)
        return *(const float4*)(xi + (size_t)gr * W + c);
    return make_float4(0.f, 0.f, 0.f, 0.f);
}

// Horizontal 11-tap (symmetric) for 4 consecutive cols.
// q0..q4 = float4s of lanes i-2, i-1, i (register), i+1, i+2.
__device__ __forceinline__ void hconv4(float4 q0, float4 q1, float4 q2,
                                       float4 q3, float4 q4, float h[4]) {
    float f[20] = { q0.x, q0.y, q0.z, q0.w,  q1.x, q1.y, q1.z, q1.w,
                    q2.x, q2.y, q2.z, q2.w,  q3.x, q3.y, q3.z, q3.w,
                    q4.x, q4.y, q4.z, q4.w };
    #pragma unroll
    for (int j = 0; j < 4; ++j) {
        float s = GW5 * f[j + 8];
        s = fmaf(GW4, f[j + 7] + f[j + 9],  s);
        s = fmaf(GW3, f[j + 6] + f[j + 10], s);
        s = fmaf(GW2, f[j + 5] + f[j + 11], s);
        s = fmaf(GW1, f[j + 4] + f[j + 12], s);
        s = fmaf(GW0, f[j + 3] + f[j + 13], s);
        h[j] = s;
    }
}

// Ring slot of input row q is (q - r0 + 5) mod 11. Invariant at entry of step K
// (output row grow, (grow-r0)%11 == K): ring holds rows grow-6..grow+4, and
// pf = row grow+5 (prefetched last step). Step: insert pf (slot (K+10)%11,
// evicting dead row grow-6), issue prefetch of row grow+6, v-pass, h-pass, store.
template<int K>
__device__ __forceinline__ void row_step(const float* __restrict__ xi,
                                         float* __restrict__ oi,
                                         float4 (&xw)[11], float4& pf,
                                         float* __restrict__ b1,
                                         float* __restrict__ b2,
                                         int c, int grow) {
    constexpr int SN = (K + 10) % 11;
    xw[SN] = pf;                                   // ring: rows grow-5..grow+5
    float4 pn = load_row(xi, grow + 6, c);         // prefetch for step K+1

    // vertical 11-tap (symmetric pairs), squares recomputed (saves 44 VGPRs)
    constexpr int SC = (K + 5) % 11;
    float4 xc = xw[SC];
    float4 v1 = f4scale(GW5, xc);
    float4 v2 = f4scale(GW5, f4mul(xc, xc));
    #define VPAIR(D, G) { constexpr int A_ = (K + 5 - (D)) % 11;                    \
                          constexpr int B_ = (K + 5 + (D)) % 11;                    \
                          float4 xa_ = xw[A_], xb_ = xw[B_];                        \
                          v1 = f4fma(G, f4add(xa_, xb_), v1);                       \
                          v2 = f4fma(G, f4add(f4mul(xa_, xa_), f4mul(xb_, xb_)), v2); }
    VPAIR(1, GW4) VPAIR(2, GW3) VPAIR(3, GW2) VPAIR(4, GW1) VPAIR(5, GW0)
    #undef VPAIR

    *(float4*)&b1[8 + c] = v1;
    *(float4*)&b2[8 + c] = v2;
    lds_fence_hard();                              // RAW: writes visible to reads

    float4 a0 = *(const float4*)&b1[c];            // lane i-2 (or left pad)
    float4 a1 = *(const float4*)&b1[c + 4];        // lane i-1
    float4 a3 = *(const float4*)&b1[c + 12];       // lane i+1
    float4 a4 = *(const float4*)&b1[c + 16];       // lane i+2 (or right pad)
    float4 d0 = *(const float4*)&b2[c];
    float4 d1 = *(const float4*)&b2[c + 4];
    float4 d3 = *(const float4*)&b2[c + 12];
    float4 d4 = *(const float4*)&b2[c + 16];
    lds_fence_order();                             // WAR vs next step's writes

    float h1[4], h2[4];
    hconv4(a0, a1, v1, a3, a4, h1);
    hconv4(d0, d1, v2, d3, d4, h2);

    float4 o;
    o.x = sqrtf(fmaf(-h1[0], h1[0], h2[0]) + 1e-6f);
    o.y = sqrtf(fmaf(-h1[1], h1[1], h2[1]) + 1e-6f);
    o.z = sqrtf(fmaf(-h1[2], h1[2], h2[2]) + 1e-6f);
    o.w = sqrtf(fmaf(-h1[3], h1[3], h2[3]) + 1e-6f);
    *(float4*)(oi + (size_t)grow * W + c) = o;

    pf = pn;
}

__global__ __launch_bounds__(256, 4) void
local_std_kernel(const float* __restrict__ x, float* __restrict__ out) {
    __shared__ float buf[4][2][LDSW];   // wave-private row buffers: 8.7 KB/block

    const int t    = threadIdx.x;
    const int wv   = t >> 6;
    const int lane = t & 63;
    const int img  = blockIdx.x;
    const float* xi = x   + (size_t)img * IMG_PIX;
    float*       oi = out + (size_t)img * IMG_PIX;

    float* b1 = buf[wv][0];
    float* b2 = buf[wv][1];

    // zero the horizontal pads once (cols [0,8) and [264,272) of both streams)
    if (lane < 32) {
        int s = (lane >> 4) & 1;
        int q = lane & 15;
        int col = (q < 8) ? q : (256 + q);
        buf[wv][s][col] = 0.f;
    }

    const int c  = lane << 2;       // this lane's 4 columns
    const int r0 = wv * BANDH;      // band start (wave-private)

    // warm-up: rows r0-5..r0+4 into slots 0..9; slot 10 is filled at step 0.
    float4 xw[11];
    #pragma unroll
    for (int i = 0; i < 10; ++i)
        xw[i] = load_row(xi, r0 - 5 + i, c);
    xw[10] = make_float4(0.f, 0.f, 0.f, 0.f);
    float4 pf = load_row(xi, r0 + 5, c);

    // sweep 64 output rows; unroll-by-11 keeps ring/template indices static.
    // Outer loop kept rolled (uniform branches) to bound I-cache footprint.
    #pragma unroll 1
    for (int ii = 0; ii < 6; ++ii) {
        const int base = ii * 11;
        #define STEP(k) if (base + (k) < BANDH) \
            row_step<(k)>(xi, oi, xw, pf, b1, b2, c, r0 + base + (k));
        STEP(0) STEP(1) STEP(2) STEP(3) STEP(4) STEP(5)
        STEP(6) STEP(7) STEP(8) STEP(9) STEP(10)
        #undef STEP
    }
}

extern "C" void kernel_launch(void* const* d_in, const int* in_sizes, int n_in,
                              void* d_out, int out_size, void* d_ws, size_t ws_size,
                              hipStream_t stream) {
    const float* x  = (const float*)d_in[0];
    float* out      = (float*)d_out;
    const int n_img = in_sizes[0] / IMG_PIX;    // 16*64 = 1024
    local_std_kernel<<<dim3(n_img), 256, 0, stream>>>(x, out);
}